// Round 8
// baseline (70.322 us; speedup 1.0000x reference)
//
#include <hip/hip_runtime.h>

#define NN     4096
#define TT     3
#define DD     20
#define EE     131072
#define ADIM   128
#define NEG    0.2f
#define NINST  (TT * EE)               // 393216 edge instances
#define PL     (NN * NN)               // 16 MB per byte-plane
#define CAP    512                     // entries per row (mean ~181, max ~250)

// ---- k0: zero 3 byte-planes (50 MB) + init scores s0 = inputs@lin_w.T+lin_b -
// grid 3072 x 256; each thread zeroes 4 uint4 (3072*256*4*16 B = 50.33 MB).
__global__ __launch_bounds__(256) void k_init(uint4* __restrict__ planes4,
                                              const float* __restrict__ inputs,
                                              const float* __restrict__ lin_w,
                                              const float* __restrict__ lin_b,
                                              float* __restrict__ s0) {
    int tid = threadIdx.x, bid = blockIdx.x;
    int gid = bid * 256 + tid;
    #pragma unroll
    for (int i = 0; i < 4; i++)
        planes4[gid + i * (3072 * 256)] = make_uint4(0u, 0u, 0u, 0u);

    if (bid < NN / 4) {
        int wid = tid >> 6, lane = tid & 63;
        int row = bid * 4 + wid;
        const float* rp = inputs + row * ADIM;
        float v = rp[lane] * lin_w[lane] + rp[lane + 64] * lin_w[lane + 64];
        #pragma unroll
        for (int off = 32; off > 0; off >>= 1) v += __shfl_down(v, off);
        if (lane == 0) s0[row] = v + lin_b[0];
    }
}

// ---- k1: idempotent byte-plane scatter (NO atomics) --------------------------
// Duplicate edges / both directions write the same value 1 -> set semantics.
__global__ __launch_bounds__(256) void k_scatter(const int* __restrict__ el,
                                                 unsigned char* __restrict__ planes) {
    int i = blockIdx.x * 256 + threadIdx.x;        // exactly NINST threads
    int t = i >> 17;                               // EE = 2^17
    int e = i & (EE - 1);
    unsigned int src = (unsigned int)el[(t * 2) * EE + e];
    unsigned int tgt = (unsigned int)el[(t * 2 + 1) * EE + e];
    unsigned char* pt = planes + (size_t)t * PL;
    pt[src * NN + tgt] = 1;
    pt[tgt * NN + src] = 1;
}

// ---- k2: fused dense-scan layer 0 + CSR build (no atomics, wave per row) ----
__global__ __launch_bounds__(256) void k_l0(const unsigned char* __restrict__ planes,
                                            unsigned int* __restrict__ cnt,
                                            unsigned short* __restrict__ entries,
                                            const float* __restrict__ s_in,
                                            const float* __restrict__ att_w,
                                            const float* __restrict__ edge_emb,
                                            float* __restrict__ s_out) {
    __shared__ float lut0[8], lut1[8], wc[4], Sred[4];
    int tid = threadIdx.x;

    if (tid < 16) {                                // layer 0 constants
        int h = tid >> 3, m = tid & 7;
        const float* w = att_w + h * (DD + 2);
        float e0 = 0.f, e1 = 0.f, e2 = 0.f;
        #pragma unroll
        for (int d = 0; d < DD; d++) {
            float wd = w[1 + d];
            e0 += edge_emb[0 * DD + d] * wd;
            e1 += edge_emb[1 * DD + d] * wd;
            e2 += edge_emb[2 * DD + d] * wd;
        }
        float l = (m & 1 ? e0 : 0.f) + (m & 2 ? e1 : 0.f) + (m & 4 ? e2 : 0.f);
        if (h) lut1[m] = l; else lut0[m] = l;
        if (m == 0) { wc[h] = w[0]; wc[2 + h] = w[DD + 1]; }
    }

    float ps = 0.f;                                // S = sum(s_in), deterministic
    for (int j = tid; j < NN; j += 256) ps += s_in[j];
    #pragma unroll
    for (int off = 32; off > 0; off >>= 1) ps += __shfl_down(ps, off);
    int wid = tid >> 6, lane = tid & 63;
    if (lane == 0) Sred[wid] = ps;
    __syncthreads();
    float S = Sred[0] + Sred[1] + Sred[2] + Sred[3];

    int row = blockIdx.x * 4 + wid;                // 1024 blocks * 4 waves
    float si = s_in[row];
    float a0 = wc[0] * si, a1 = wc[1] * si;
    float b0 = wc[2],      b1 = wc[3];
    const uint4* r0 = (const uint4*)(planes + (size_t)row * NN);
    const uint4* r1 = (const uint4*)(planes + (size_t)PL     + (size_t)row * NN);
    const uint4* r2 = (const uint4*)(planes + (size_t)PL * 2 + (size_t)row * NN);
    unsigned short* erow = entries + (size_t)row * CAP;

    float num0 = 0.f, den0 = 0.f, num1 = 0.f, den1 = 0.f;
    unsigned int base = 0;
    #pragma unroll
    for (int k = 0; k < 4; k++) {                  // 4 x (64 lanes x 16 B) = 4096
        uint4 A = r0[k * 64 + lane];
        uint4 B = r1[k * 64 + lane];
        uint4 C = r2[k * 64 + lane];
        unsigned int o0 = A.x | B.x | C.x, o1 = A.y | B.y | C.y;
        unsigned int o2 = A.z | B.z | C.z, o3 = A.w | B.w | C.w;
        unsigned int c = __popc(o0) + __popc(o1) + __popc(o2) + __popc(o3);

        unsigned int p = c;                        // wave-inclusive scan
        #pragma unroll
        for (int off = 1; off < 64; off <<= 1) {
            unsigned int v = __shfl_up(p, off);
            if (lane >= off) p += v;
        }
        unsigned int pos = base + (p - c);         // exclusive prefix
        int j0 = k * 1024 + lane * 16;

        #pragma unroll
        for (int q = 0; q < 4; q++) {
            unsigned int w0 = q == 0 ? A.x : q == 1 ? A.y : q == 2 ? A.z : A.w;
            unsigned int w1 = q == 0 ? B.x : q == 1 ? B.y : q == 2 ? B.z : B.w;
            unsigned int w2 = q == 0 ? C.x : q == 1 ? C.y : q == 2 ? C.z : C.w;
            if (!(w0 | w1 | w2)) continue;
            #pragma unroll
            for (int bb = 0; bb < 4; bb++) {
                unsigned int nib = ((w0 >> (bb * 8)) & 1u)
                                 | (((w1 >> (bb * 8)) & 1u) << 1)
                                 | (((w2 >> (bb * 8)) & 1u) << 2);
                if (!nib) continue;
                int j = j0 + q * 4 + bb;
                float c2 = (float)__popc(nib);
                float sj = s_in[j];
                float l0 = c2 * (a0 + b0 * sj) + lut0[nib];
                l0 = (l0 > 0.f) ? l0 : NEG * l0;
                float x0 = __expf(l0) - 1.0f;
                num0 += x0 * sj; den0 += x0;
                float l1 = c2 * (a1 + b1 * sj) + lut1[nib];
                l1 = (l1 > 0.f) ? l1 : NEG * l1;
                float x1 = __expf(l1) - 1.0f;
                num1 += x1 * sj; den1 += x1;
                erow[pos++] = (unsigned short)(j | (nib << 12));
            }
        }
        base += __shfl(p, 63);                     // wave total this k
    }
    if (lane == 0) cnt[row] = base;

    #pragma unroll
    for (int off = 32; off > 0; off >>= 1) {
        num0 += __shfl_down(num0, off); den0 += __shfl_down(den0, off);
        num1 += __shfl_down(num1, off); den1 += __shfl_down(den1, off);
    }
    if (lane == 0) {
        float o0v = (S + num0) / ((float)NN + den0);
        float o1v = (S + num1) / ((float)NN + den1);
        s_out[row] = 0.5f * (o0v + o1v);
    }
}

// ---- k3: layer 1 over compact CSR (row per wave) ----------------------------
__global__ __launch_bounds__(256) void k_l1(const unsigned int* __restrict__ cnt,
                                            const unsigned short* __restrict__ entries,
                                            const float* __restrict__ s_in,
                                            const float* __restrict__ att_w,
                                            const float* __restrict__ edge_emb,
                                            float* __restrict__ s_out) {
    __shared__ float lut0[8], lut1[8], wc[4], Sred[4];
    int tid = threadIdx.x;

    if (tid < 16) {                                // layer 1 constants
        int h = tid >> 3, m = tid & 7;
        const float* w = att_w + (2 + h) * (DD + 2);
        float e0 = 0.f, e1 = 0.f, e2 = 0.f;
        #pragma unroll
        for (int d = 0; d < DD; d++) {
            float wd = w[1 + d];
            e0 += edge_emb[0 * DD + d] * wd;
            e1 += edge_emb[1 * DD + d] * wd;
            e2 += edge_emb[2 * DD + d] * wd;
        }
        float l = (m & 1 ? e0 : 0.f) + (m & 2 ? e1 : 0.f) + (m & 4 ? e2 : 0.f);
        if (h) lut1[m] = l; else lut0[m] = l;
        if (m == 0) { wc[h] = w[0]; wc[2 + h] = w[DD + 1]; }
    }

    float ps = 0.f;
    for (int j = tid; j < NN; j += 256) ps += s_in[j];
    #pragma unroll
    for (int off = 32; off > 0; off >>= 1) ps += __shfl_down(ps, off);
    int wid = tid >> 6, lane = tid & 63;
    if (lane == 0) Sred[wid] = ps;
    __syncthreads();
    float S = Sred[0] + Sred[1] + Sred[2] + Sred[3];

    int row = blockIdx.x * 4 + wid;
    float si = s_in[row];
    float a0 = wc[0] * si, a1 = wc[1] * si;
    float b0 = wc[2],      b1 = wc[3];
    unsigned int n = cnt[row];
    const unsigned short* ent = entries + (size_t)row * CAP;

    float num0 = 0.f, den0 = 0.f, num1 = 0.f, den1 = 0.f;
    for (unsigned int i = lane; i < n; i += 64) {
        unsigned int v = ent[i];
        unsigned int j = v & 0xFFFu, nib = v >> 12;
        float c  = (float)__popc(nib);
        float sj = s_in[j];
        float l0 = c * (a0 + b0 * sj) + lut0[nib];
        l0 = (l0 > 0.f) ? l0 : NEG * l0;
        float x0 = __expf(l0) - 1.0f;
        num0 += x0 * sj; den0 += x0;
        float l1 = c * (a1 + b1 * sj) + lut1[nib];
        l1 = (l1 > 0.f) ? l1 : NEG * l1;
        float x1 = __expf(l1) - 1.0f;
        num1 += x1 * sj; den1 += x1;
    }

    #pragma unroll
    for (int off = 32; off > 0; off >>= 1) {
        num0 += __shfl_down(num0, off); den0 += __shfl_down(den0, off);
        num1 += __shfl_down(num1, off); den1 += __shfl_down(den1, off);
    }
    if (lane == 0) {
        float o0 = (S + num0) / ((float)NN + den0);
        float o1 = (S + num1) / ((float)NN + den1);
        s_out[row] = 0.5f * (o0 + o1);
    }
}

// ---- host-side launcher ------------------------------------------------------
extern "C" void kernel_launch(void* const* d_in, const int* in_sizes, int n_in,
                              void* d_out, int out_size, void* d_ws, size_t ws_size,
                              hipStream_t stream) {
    const float* inputs   = (const float*)d_in[0];
    const float* lin_w    = (const float*)d_in[1];
    const float* lin_b    = (const float*)d_in[2];
    const float* edge_emb = (const float*)d_in[3];
    const float* att_w    = (const float*)d_in[4];
    const int*   el       = (const int*)d_in[5];
    float* out = (float*)d_out;

    char* ws = (char*)d_ws;
    unsigned char*  planes  = (unsigned char*)ws;                         // 50.33 MB
    unsigned short* entries = (unsigned short*)(ws + 50331648);           // 4 MB
    unsigned int*   cnt     = (unsigned int*)(ws + 54525952);             // 16 KB
    float*          s0      = (float*)(ws + 54542336);                    // 16 KB
    float*          s1      = (float*)(ws + 54558720);                    // 16 KB

    k_init   <<<3072, 256, 0, stream>>>((uint4*)planes, inputs, lin_w, lin_b, s0);
    k_scatter<<<NINST / 256, 256, 0, stream>>>(el, planes);
    k_l0     <<<1024, 256, 0, stream>>>(planes, cnt, entries, s0, att_w, edge_emb, s1);
    k_l1     <<<1024, 256, 0, stream>>>(cnt, entries, s1, att_w, edge_emb, out);
}

// Round 9
// 65.693 us; speedup vs baseline: 1.0705x; 1.0705x over previous
//
#include <hip/hip_runtime.h>

#define NN     4096
#define TT     3
#define DD     20
#define EE     131072
#define ADIM   128
#define NEG    0.2f
#define NEDGE  (TT * EE)               // 393216 edges
#define NINST  (2 * NEDGE)             // 786432 directed instances
#define NB     256                     // histogram/scatter blocks
#define IPB    (NINST / NB)            // 3072 instances per block
#define CAP    512                     // compact CSR entries per row (max ~250)

// ---- k_hist: per-block LDS row-histogram + fused score init ------------------
__global__ __launch_bounds__(256) void k_hist(const int* __restrict__ el,
                                              unsigned int* __restrict__ histo,
                                              const float* __restrict__ inputs,
                                              const float* __restrict__ lin_w,
                                              const float* __restrict__ lin_b,
                                              float* __restrict__ s0) {
    __shared__ unsigned int h[NN];
    int tid = threadIdx.x, bid = blockIdx.x;
    for (int i = tid; i < NN; i += 256) h[i] = 0u;
    __syncthreads();
    int base = bid * IPB;
    #pragma unroll
    for (int k = 0; k < IPB / 256; k++) {          // 12 iters
        int inst = base + k * 256 + tid;
        int edge = inst >> 1, dir = inst & 1;
        int t = edge >> 17;                        // EE = 2^17
        int e = edge & (EE - 1);
        unsigned int a = (unsigned int)el[(t * 2) * EE + e];
        unsigned int b = (unsigned int)el[(t * 2 + 1) * EE + e];
        unsigned int row = dir ? b : a;
        atomicAdd(&h[row], 1u);
    }
    __syncthreads();
    for (int i = tid; i < NN; i += 256) histo[bid * NN + i] = h[i];

    // fused: s0 = inputs @ lin_w.T + lin_b   (1024 waves x 4 rows)
    int wid = tid >> 6, lane = tid & 63;
    int wg = bid * 4 + wid;                        // 0..1023
    #pragma unroll
    for (int r = 0; r < 4; r++) {
        int row = wg * 4 + r;
        const float* rp = inputs + row * ADIM;
        float v = rp[lane] * lin_w[lane] + rp[lane + 64] * lin_w[lane + 64];
        #pragma unroll
        for (int off = 32; off > 0; off >>= 1) v += __shfl_down(v, off);
        if (lane == 0) s0[row] = v + lin_b[0];
    }
}

// ---- k_prefix1: per-bin running sum across blocks (in-place), bin totals ----
__global__ __launch_bounds__(64) void k_prefix1(unsigned int* __restrict__ histo,
                                                unsigned int* __restrict__ bintotal) {
    int b = blockIdx.x * 64 + threadIdx.x;         // 64 blocks x 64 = 4096
    unsigned int run = 0u;
    for (int blk = 0; blk < NB; blk++) {
        unsigned int h = histo[blk * NN + b];
        histo[blk * NN + b] = run;                 // block-local exclusive base
        run += h;
    }
    bintotal[b] = run;
}

// ---- k_prefix2: exclusive scan of 4096 bin totals -> rowstart ---------------
__global__ __launch_bounds__(1024) void k_prefix2(const unsigned int* __restrict__ bintotal,
                                                  unsigned int* __restrict__ rowstart) {
    __shared__ unsigned int ws[16];
    int tid = threadIdx.x, wid = tid >> 6, lane = tid & 63;
    unsigned int a0 = bintotal[tid * 4 + 0];
    unsigned int a1 = bintotal[tid * 4 + 1];
    unsigned int a2 = bintotal[tid * 4 + 2];
    unsigned int a3 = bintotal[tid * 4 + 3];
    unsigned int s = a0 + a1 + a2 + a3;
    unsigned int p = s;                            // wave-inclusive scan
    #pragma unroll
    for (int off = 1; off < 64; off <<= 1) {
        unsigned int t = __shfl_up(p, off);
        if (lane >= off) p += t;
    }
    if (lane == 63) ws[wid] = p;
    __syncthreads();
    if (tid < 16) {                                // scan the 16 wave totals
        unsigned int w = ws[tid];
        unsigned int q = w;
        #pragma unroll
        for (int off = 1; off < 16; off <<= 1) {
            unsigned int t = __shfl_up(q, off);
            if (lane >= off) q += t;
        }
        ws[tid] = q - w;                           // exclusive
    }
    __syncthreads();
    unsigned int base = ws[wid] + (p - s);
    rowstart[tid * 4 + 0] = base;
    rowstart[tid * 4 + 1] = base + a0;
    rowstart[tid * 4 + 2] = base + a0 + a1;
    rowstart[tid * 4 + 3] = base + a0 + a1 + a2;
}

// ---- k_scat: ranked scatter into row buckets (LDS counters, no global atomics)
__global__ __launch_bounds__(256) void k_scat(const int* __restrict__ el,
                                              const unsigned int* __restrict__ histo,
                                              const unsigned int* __restrict__ rowstart,
                                              unsigned short* __restrict__ bucket) {
    __shared__ unsigned int c[NN];
    int tid = threadIdx.x, bid = blockIdx.x;
    for (int i = tid; i < NN; i += 256) c[i] = 0u;
    __syncthreads();
    int base = bid * IPB;
    #pragma unroll
    for (int k = 0; k < IPB / 256; k++) {
        int inst = base + k * 256 + tid;
        int edge = inst >> 1, dir = inst & 1;
        int t = edge >> 17;
        int e = edge & (EE - 1);
        unsigned int a = (unsigned int)el[(t * 2) * EE + e];
        unsigned int b = (unsigned int)el[(t * 2 + 1) * EE + e];
        unsigned int row = dir ? b : a;
        unsigned int col = dir ? a : b;
        unsigned int r = atomicAdd(&c[row], 1u);
        unsigned int pos = rowstart[row] + histo[bid * NN + row] + r;
        bucket[pos] = (unsigned short)(col | ((unsigned int)t << 12));
    }
}

// ---- k_l0: per-row LDS nibble-mask dedup + layer 0 + compact CSR emit -------
__global__ __launch_bounds__(256) void k_l0(const unsigned int* __restrict__ rowstart,
                                            const unsigned int* __restrict__ bintotal,
                                            const unsigned short* __restrict__ bucket,
                                            unsigned int* __restrict__ cnt2,
                                            unsigned short* __restrict__ entries2,
                                            const float* __restrict__ s_in,
                                            const float* __restrict__ att_w,
                                            const float* __restrict__ edge_emb,
                                            float* __restrict__ s_out) {
    __shared__ unsigned int mask[4][512];          // 2 KB nibble-mask per wave/row
    __shared__ float lut0[8], lut1[8], wc[4], Sred[4];
    int tid = threadIdx.x, wid = tid >> 6, lane = tid & 63;

    if (tid < 16) {                                // layer 0 constants
        int h = tid >> 3, m = tid & 7;
        const float* w = att_w + h * (DD + 2);
        float e0 = 0.f, e1 = 0.f, e2 = 0.f;
        #pragma unroll
        for (int d = 0; d < DD; d++) {
            float wd = w[1 + d];
            e0 += edge_emb[0 * DD + d] * wd;
            e1 += edge_emb[1 * DD + d] * wd;
            e2 += edge_emb[2 * DD + d] * wd;
        }
        float l = (m & 1 ? e0 : 0.f) + (m & 2 ? e1 : 0.f) + (m & 4 ? e2 : 0.f);
        if (h) lut1[m] = l; else lut0[m] = l;
        if (m == 0) { wc[h] = w[0]; wc[2 + h] = w[DD + 1]; }
    }

    float ps = 0.f;                                // S = sum(s_in), deterministic
    for (int j = tid; j < NN; j += 256) ps += s_in[j];
    #pragma unroll
    for (int off = 32; off > 0; off >>= 1) ps += __shfl_down(ps, off);
    if (lane == 0) Sred[wid] = ps;

    // zero this wave's mask, then OR in the row's bucketed entries
    for (int i = lane; i < 512; i += 64) mask[wid][i] = 0u;
    int row = blockIdx.x * 4 + wid;
    unsigned int n = bintotal[row], st = rowstart[row];
    for (unsigned int i = lane; i < n; i += 64) {
        unsigned int v = bucket[st + i];
        unsigned int col = v & 0xFFFu, t = v >> 12;
        atomicOr(&mask[wid][col >> 3], 1u << (((col & 7u) << 2) + t));
    }
    __syncthreads();                               // covers lut/Sred/mask
    float S = Sred[0] + Sred[1] + Sred[2] + Sred[3];

    float si = s_in[row];
    float a0 = wc[0] * si, a1 = wc[1] * si;
    float b0 = wc[2],      b1 = wc[3];
    unsigned short* erow = entries2 + (size_t)row * CAP;

    float num0 = 0.f, den0 = 0.f, num1 = 0.f, den1 = 0.f;
    unsigned int base = 0;
    #pragma unroll
    for (int k = 0; k < 8; k++) {                  // 512 words, 8 per lane
        unsigned int w = mask[wid][k * 64 + lane];
        unsigned int y = w | (w >> 1); y |= (y >> 2); y &= 0x11111111u;
        unsigned int cc = __popc(y);
        unsigned int p = cc;                       // wave-inclusive scan
        #pragma unroll
        for (int off = 1; off < 64; off <<= 1) {
            unsigned int v = __shfl_up(p, off);
            if (lane >= off) p += v;
        }
        unsigned int pos = base + (p - cc);        // exclusive prefix
        if (w) {
            int jb = (k * 64 + lane) << 3;
            #pragma unroll
            for (int kk = 0; kk < 8; kk++) {
                unsigned int nib = (w >> (kk * 4)) & 0xFu;
                if (!nib) continue;
                int j = jb + kk;
                float c2 = (float)__popc(nib);
                float sj = s_in[j];
                float l0 = c2 * (a0 + b0 * sj) + lut0[nib];
                l0 = (l0 > 0.f) ? l0 : NEG * l0;
                float x0 = __expf(l0) - 1.0f;
                num0 += x0 * sj; den0 += x0;
                float l1 = c2 * (a1 + b1 * sj) + lut1[nib];
                l1 = (l1 > 0.f) ? l1 : NEG * l1;
                float x1 = __expf(l1) - 1.0f;
                num1 += x1 * sj; den1 += x1;
                erow[pos++] = (unsigned short)(j | (nib << 12));
            }
        }
        base += __shfl(p, 63);
    }
    if (lane == 0) cnt2[row] = base;

    #pragma unroll
    for (int off = 32; off > 0; off >>= 1) {
        num0 += __shfl_down(num0, off); den0 += __shfl_down(den0, off);
        num1 += __shfl_down(num1, off); den1 += __shfl_down(den1, off);
    }
    if (lane == 0) {
        float o0 = (S + num0) / ((float)NN + den0);
        float o1 = (S + num1) / ((float)NN + den1);
        s_out[row] = 0.5f * (o0 + o1);
    }
}

// ---- k_l1: layer 1 over compact CSR (row per wave) --------------------------
__global__ __launch_bounds__(256) void k_l1(const unsigned int* __restrict__ cnt2,
                                            const unsigned short* __restrict__ entries2,
                                            const float* __restrict__ s_in,
                                            const float* __restrict__ att_w,
                                            const float* __restrict__ edge_emb,
                                            float* __restrict__ s_out) {
    __shared__ float lut0[8], lut1[8], wc[4], Sred[4];
    int tid = threadIdx.x;

    if (tid < 16) {                                // layer 1 constants
        int h = tid >> 3, m = tid & 7;
        const float* w = att_w + (2 + h) * (DD + 2);
        float e0 = 0.f, e1 = 0.f, e2 = 0.f;
        #pragma unroll
        for (int d = 0; d < DD; d++) {
            float wd = w[1 + d];
            e0 += edge_emb[0 * DD + d] * wd;
            e1 += edge_emb[1 * DD + d] * wd;
            e2 += edge_emb[2 * DD + d] * wd;
        }
        float l = (m & 1 ? e0 : 0.f) + (m & 2 ? e1 : 0.f) + (m & 4 ? e2 : 0.f);
        if (h) lut1[m] = l; else lut0[m] = l;
        if (m == 0) { wc[h] = w[0]; wc[2 + h] = w[DD + 1]; }
    }

    float ps = 0.f;
    for (int j = tid; j < NN; j += 256) ps += s_in[j];
    #pragma unroll
    for (int off = 32; off > 0; off >>= 1) ps += __shfl_down(ps, off);
    int wid = tid >> 6, lane = tid & 63;
    if (lane == 0) Sred[wid] = ps;
    __syncthreads();
    float S = Sred[0] + Sred[1] + Sred[2] + Sred[3];

    int row = blockIdx.x * 4 + wid;
    float si = s_in[row];
    float a0 = wc[0] * si, a1 = wc[1] * si;
    float b0 = wc[2],      b1 = wc[3];
    unsigned int n = cnt2[row];
    const unsigned short* ent = entries2 + (size_t)row * CAP;

    float num0 = 0.f, den0 = 0.f, num1 = 0.f, den1 = 0.f;
    for (unsigned int i = lane; i < n; i += 64) {
        unsigned int v = ent[i];
        unsigned int j = v & 0xFFFu, nib = v >> 12;
        float c  = (float)__popc(nib);
        float sj = s_in[j];
        float l0 = c * (a0 + b0 * sj) + lut0[nib];
        l0 = (l0 > 0.f) ? l0 : NEG * l0;
        float x0 = __expf(l0) - 1.0f;
        num0 += x0 * sj; den0 += x0;
        float l1 = c * (a1 + b1 * sj) + lut1[nib];
        l1 = (l1 > 0.f) ? l1 : NEG * l1;
        float x1 = __expf(l1) - 1.0f;
        num1 += x1 * sj; den1 += x1;
    }

    #pragma unroll
    for (int off = 32; off > 0; off >>= 1) {
        num0 += __shfl_down(num0, off); den0 += __shfl_down(den0, off);
        num1 += __shfl_down(num1, off); den1 += __shfl_down(den1, off);
    }
    if (lane == 0) {
        float o0 = (S + num0) / ((float)NN + den0);
        float o1 = (S + num1) / ((float)NN + den1);
        s_out[row] = 0.5f * (o0 + o1);
    }
}

// ---- host-side launcher ------------------------------------------------------
extern "C" void kernel_launch(void* const* d_in, const int* in_sizes, int n_in,
                              void* d_out, int out_size, void* d_ws, size_t ws_size,
                              hipStream_t stream) {
    const float* inputs   = (const float*)d_in[0];
    const float* lin_w    = (const float*)d_in[1];
    const float* lin_b    = (const float*)d_in[2];
    const float* edge_emb = (const float*)d_in[3];
    const float* att_w    = (const float*)d_in[4];
    const int*   el       = (const int*)d_in[5];
    float* out = (float*)d_out;

    char* ws = (char*)d_ws;
    unsigned int*   histo    = (unsigned int*)ws;                         // 4 MB
    unsigned int*   bintotal = (unsigned int*)(ws + 4194304);             // 16 KB
    unsigned int*   rowstart = (unsigned int*)(ws + 4210688);             // 16 KB
    unsigned short* bucket   = (unsigned short*)(ws + 4227072);           // 1.5 MB
    unsigned short* entries2 = (unsigned short*)(ws + 5799936);           // 4 MB
    unsigned int*   cnt2     = (unsigned int*)(ws + 9994240);             // 16 KB
    float*          s0       = (float*)(ws + 10010624);                   // 16 KB
    float*          s1       = (float*)(ws + 10027008);                   // 16 KB

    k_hist   <<<NB, 256, 0, stream>>>(el, histo, inputs, lin_w, lin_b, s0);
    k_prefix1<<<64, 64, 0, stream>>>(histo, bintotal);
    k_prefix2<<<1, 1024, 0, stream>>>(bintotal, rowstart);
    k_scat   <<<NB, 256, 0, stream>>>(el, histo, rowstart, bucket);
    k_l0     <<<1024, 256, 0, stream>>>(rowstart, bintotal, bucket, cnt2, entries2,
                                        s0, att_w, edge_emb, s1);
    k_l1     <<<1024, 256, 0, stream>>>(cnt2, entries2, s1, att_w, edge_emb, out);
}